// Round 10
// baseline (532.313 us; speedup 1.0000x reference)
//
#include <hip/hip_runtime.h>
#include <hip/hip_bf16.h>
#include <hip/hip_fp16.h>

#define NF 100000
#define NH 49152
#define EDG 400000
#define SLOTD 24
#define SLOTE 32

typedef __attribute__((ext_vector_type(8))) short short8;
typedef __attribute__((ext_vector_type(4))) float float4v;
typedef unsigned short u16;
typedef unsigned int u32;

struct H4 { __half2 a, b; };   // 4 fp16 channels, 8 B

__device__ __forceinline__ u16 f2b(float x) {
    u32 u = __float_as_uint(x);
    u32 r = u + 0x7FFFu + ((u >> 16) & 1u);
    return (u16)(r >> 16);
}
__device__ __forceinline__ float fast_tanh(float x) {
    float ex = __expf(2.0f * x);
    return 1.0f - 2.0f / (ex + 1.0f);
}

// ---------------- one-kernel init: csrD sentinel, csrE zeros, deg/cnt zeros, m zero row ----------------
#define PN1 (NF * 12)            /* csrD as u32: NF*24/2 */
#define PN2 (NH * SLOTE)         /* csrE u32 */
#define PN3 298304               /* deg_se,deg_sd,cntD,cntE */
#define PN4 128                  /* m zero row as u32 */
__global__ void prefill(u32* __restrict__ csrD32, u32* __restrict__ csrE,
                        u32* __restrict__ degcnt, u32* __restrict__ mzero) {
    int i = blockIdx.x * 256 + threadIdx.x;
    if (i < PN1) csrD32[i] = ((u32)NH << 16) | (u32)NH;
    else if (i < PN1 + PN2) csrE[i - PN1] = 0u;
    else if (i < PN1 + PN2 + PN3) degcnt[i - PN1 - PN2] = 0u;
    else if (i < PN1 + PN2 + PN3 + PN4) mzero[i - PN1 - PN2 - PN3] = 0u;
}

// ---------------- one-pass slotted CSR build (both graphs) + src-degree counts ----------------
__global__ void fill_slotted(const int* __restrict__ enc_src, const int* __restrict__ enc_dst,
                             const int* __restrict__ dec_src, const int* __restrict__ dec_dst,
                             int* __restrict__ cntD, u16* __restrict__ csrD, float* __restrict__ deg_sd,
                             int* __restrict__ cntE, u32* __restrict__ csrE, float* __restrict__ deg_se) {
    int e = blockIdx.x * 256 + threadIdx.x;
    if (e >= EDG) return;
    int ds = dec_src[e], dd = dec_dst[e];
    int i1 = atomicAdd(&cntD[dd], 1);
    if (i1 < SLOTD) csrD[(size_t)dd * SLOTD + i1] = (u16)ds;   // dec_src < NH < 65536
    atomicAdd(&deg_sd[ds], 1.0f);
    int es = enc_src[e], ed = enc_dst[e];
    int i2 = atomicAdd(&cntE[ed], 1);
    if (i2 < SLOTE) csrE[(size_t)ed * SLOTE + i2] = (u32)es;
    atomicAdd(&deg_se[es], 1.0f);
}

// ---------------- bf16 B-fragment prep + uv prep (blocks 0..27 frag, 28 uv) ----------------
__global__ void prep_small(const float* __restrict__ W_dec, const float* __restrict__ W_a1,
                           u16* __restrict__ fragWdec, u16* __restrict__ fragWa1,
                           const float* __restrict__ W_lin, const float* __restrict__ b_lin,
                           const float* __restrict__ b_a1, const float* __restrict__ W_o,
                           float* __restrict__ uvs) {
    const int b = blockIdx.x;
    if (b < 28) {
        int gid = b * 256 + threadIdx.x;   // 0..7167
        if (gid >= 7168) return;
        int L = gid & 63;
        int f = gid >> 6;          // 0..95: W_dec (t=f>>3); 96..111: W_a1
        int q = L >> 4, cb = L & 15;
        if (f < 96) {
            int fr = f & 7;
            int c = fr >> 1, kc = fr & 1;
            int k0 = kc * 32 + q * 8;
            int nn = c * 16 + cb;
            int t = f >> 3;
            #pragma unroll
            for (int j = 0; j < 8; ++j)
                fragWdec[(f * 64 + L) * 8 + j] = f2b(W_dec[t * 4096 + (k0 + j) * 64 + nn]);
        } else {
            int fr = f - 96;
            int c2 = fr >> 1, kc = fr & 1;
            int k0 = kc * 32 + q * 8;
            int nn = c2 * 16 + cb;
            #pragma unroll
            for (int j = 0; j < 8; ++j)
                fragWa1[(fr * 64 + L) * 8 + j] = f2b(W_a1[(k0 + j) * 128 + nn]);
        }
    } else {
        int k = threadIdx.x;
        if (k < 128) {
            float su = 0.f, sv = 0.f;
            for (int h = 0; h < 64; ++h) {
                su = fmaf(W_lin[h], W_a1[h * 128 + k], su);
                sv = fmaf(b_lin[h], W_a1[h * 128 + k], sv);
            }
            uvs[k] = su;
            uvs[128 + k] = sv + b_a1[k];
            if (k == 0) {
                float a = 0.f, bb = 0.f;
                for (int h = 0; h < 64; ++h) {
                    a = fmaf(W_lin[h], W_o[h], a);
                    bb = fmaf(b_lin[h], W_o[h], bb);
                }
                uvs[256] = a;  // wlo
                uvs[257] = bb; // blo
            }
        }
    }
}

// ---------------- tabulate g(y) = sum_k tanh(y*u_k + v_k) * w_k over y in [-32,32] ----------------
__global__ void build_gtab(const float* __restrict__ uvs, const float* __restrict__ W_a2,
                           float* __restrict__ gtab) {
    int i = blockIdx.x * 256 + threadIdx.x;
    if (i > 16384) return;
    float y = fmaf((float)i, 1.f / 256.f, -32.f);
    float s = 0.f;
    for (int k = 0; k < 128; ++k)
        s = fmaf(fast_tanh(fmaf(y, uvs[k], uvs[128 + k])), W_a2[k], s);
    gtab[i] = s;
}

// ---------------- encoder aggregation: agg[dst][0..15] = sum nan_to_num(feat[src])*c_se[src] ----------
__global__ __launch_bounds__(256) void enc_gather(const float* __restrict__ feat,
                                                  const float* __restrict__ deg_se,
                                                  const int* __restrict__ cntE,
                                                  const u32* __restrict__ csrE,
                                                  float* __restrict__ agg) {
    const int tid = threadIdx.x, lane = tid & 63, wid = tid >> 6;
    const int grp = lane >> 2, l = lane & 3;      // 16 quads of 4 lanes
    const int dst = blockIdx.x * 64 + wid * 16 + grp;
    int cnt = cntE[dst];
    if (cnt > SLOTE) cnt = SLOTE;
    const u32* cp = csrE + (size_t)dst * SLOTE;
    float4 a = {0.f, 0.f, 0.f, 0.f};
    if (l < 3) {
        for (int e = 0; e < cnt; e += 4) {
            u32 s0 = cp[e], s1 = cp[e + 1], s2 = cp[e + 2], s3 = cp[e + 3];
            float c0 = rsqrtf(fmaxf(deg_se[s0], 1.0f));
            float c1 = (e + 1 < cnt) ? rsqrtf(fmaxf(deg_se[s1], 1.0f)) : 0.f;
            float c2 = (e + 2 < cnt) ? rsqrtf(fmaxf(deg_se[s2], 1.0f)) : 0.f;
            float c3 = (e + 3 < cnt) ? rsqrtf(fmaxf(deg_se[s3], 1.0f)) : 0.f;
            float4 w0 = *(const float4*)(feat + (size_t)s0 * 12 + l * 4);
            float4 w1 = *(const float4*)(feat + (size_t)s1 * 12 + l * 4);
            float4 w2 = *(const float4*)(feat + (size_t)s2 * 12 + l * 4);
            float4 w3 = *(const float4*)(feat + (size_t)s3 * 12 + l * 4);
            w0.x = (w0.x != w0.x) ? 0.f : w0.x; w0.y = (w0.y != w0.y) ? 0.f : w0.y;
            w0.z = (w0.z != w0.z) ? 0.f : w0.z; w0.w = (w0.w != w0.w) ? 0.f : w0.w;
            w1.x = (w1.x != w1.x) ? 0.f : w1.x; w1.y = (w1.y != w1.y) ? 0.f : w1.y;
            w1.z = (w1.z != w1.z) ? 0.f : w1.z; w1.w = (w1.w != w1.w) ? 0.f : w1.w;
            w2.x = (w2.x != w2.x) ? 0.f : w2.x; w2.y = (w2.y != w2.y) ? 0.f : w2.y;
            w2.z = (w2.z != w2.z) ? 0.f : w2.z; w2.w = (w2.w != w2.w) ? 0.f : w2.w;
            w3.x = (w3.x != w3.x) ? 0.f : w3.x; w3.y = (w3.y != w3.y) ? 0.f : w3.y;
            w3.z = (w3.z != w3.z) ? 0.f : w3.z; w3.w = (w3.w != w3.w) ? 0.f : w3.w;
            a.x = fmaf(w0.x, c0, fmaf(w1.x, c1, fmaf(w2.x, c2, fmaf(w3.x, c3, a.x))));
            a.y = fmaf(w0.y, c0, fmaf(w1.y, c1, fmaf(w2.y, c2, fmaf(w3.y, c3, a.y))));
            a.z = fmaf(w0.z, c0, fmaf(w1.z, c1, fmaf(w2.z, c2, fmaf(w3.z, c3, a.z))));
            a.w = fmaf(w0.w, c0, fmaf(w1.w, c1, fmaf(w2.w, c2, fmaf(w3.w, c3, a.w))));
        }
    }
    *(float4*)(agg + (size_t)dst * 16 + l * 4) = a;   // l==3 writes zero pad
}

// ---------------- m chunk (node-major, FP16): m[n][tt][h] for t = t0..t0+3 ----------------
__global__ void make_chunk(const float* __restrict__ agg, const int* __restrict__ cntE,
                           const float* __restrict__ deg_sd, const float* __restrict__ W_enc,
                           const float* __restrict__ b_enc, const float* __restrict__ W_proc,
                           const float* __restrict__ b_proc, u16* __restrict__ m, int t0) {
    int gid = blockIdx.x * 256 + threadIdx.x;
    if (gid >= NH * 64) return;
    int n = gid >> 6, h = gid & 63;
    float cde = rsqrtf(fmaxf((float)cntE[n], 1.0f));
    float csd = rsqrtf(fmaxf(deg_sd[n], 1.0f));
    float he[12];
    #pragma unroll
    for (int ti = 0; ti < 12; ++ti) {
        float a = agg[n * 16 + ti] * cde;
        float x = fmaf(a, W_enc[ti * 64 + h], b_enc[ti * 64 + h]);
        he[ti] = x > 0.f ? x : 0.01f * x;
    }
    #pragma unroll
    for (int tt = 0; tt < 4; ++tt) {
        int t = t0 + tt;
        float s = b_proc[t];
        #pragma unroll
        for (int ti = 0; ti < 12; ++ti) s = fmaf(he[ti], W_proc[ti * 12 + t], s);
        s = fmaxf(s, 0.f) * csd;
        m[(size_t)n * 256 + tt * 64 + h] = __half_as_ushort(__float2half(s));
    }
}

// ---------------- decoder chunk pass: packed-fp16 gather + tt-multiplexed LDS + MFMA GEMMs ----------
__global__ __launch_bounds__(256) void dec_batch(
    const u16* __restrict__ m, const int* __restrict__ cntD, const u16* __restrict__ csrD,
    const u16* __restrict__ fragWdec, const u16* __restrict__ fragWa1,
    const float* __restrict__ b_dec, const float* __restrict__ b_a1,
    const float* __restrict__ W_a2, const float* __restrict__ W_o,
    float* __restrict__ S1, float* __restrict__ PW, int t0) {
    __shared__ __align__(16) u16 zs[11264];   // 4 waves x (2 tt-regions x 16 rows x 88)

    const int tid = threadIdx.x, lane = tid & 63, wid = tid >> 6;
    const int nw = blockIdx.x * 64 + wid * 16;
    const int g16 = lane >> 4, c16 = lane & 15;
    u16* zw0 = zs + wid * 2816;

    // ---- hoisted per-node metadata (4 independent loads) ----
    int cdw[4]; float cdd[4]; const u16* cpp[4];
    #pragma unroll
    for (int k = 0; k < 4; ++k) {
        int n = nw + g16 * 4 + k;
        bool v = (n < NF);
        int nn = v ? n : 0;
        int cd = cntD[nn];
        cdd[k] = v ? rsqrtf(fmaxf((float)cd, 1.0f)) : 0.f;
        int w = cd > SLOTD ? SLOTD : ((cd + 3) & ~3);
        cdw[k] = v ? w : 0;
        cpp[k] = csrD + (size_t)nn * SLOTD;
    }

    __half2 def[4][2][2];   // deferred tt=2,3 accumulators per node

    // ---- gather: 4 nodes per 16-lane group, all 4 tt accumulated in regs ----
    #pragma unroll
    for (int k = 0; k < 4; ++k) {
        int j = g16 * 4 + k;
        __half2 acc[4][2];
        #pragma unroll
        for (int tt = 0; tt < 4; ++tt) {
            acc[tt][0] = __half2{__half(0.f), __half(0.f)};
            acc[tt][1] = __half2{__half(0.f), __half(0.f)};
        }
        const u16* cp = cpp[k];
        for (int e = 0; e < cdw[k]; e += 4) {
            uint2 ss = *(const uint2*)(cp + e);          // sentinel-padded: always safe
            int s0 = ss.x & 0xFFFF, s1 = ss.x >> 16;
            int s2 = ss.y & 0xFFFF, s3 = ss.y >> 16;
            const u16* r0 = m + (size_t)s0 * 256 + c16 * 4;
            const u16* r1 = m + (size_t)s1 * 256 + c16 * 4;
            const u16* r2 = m + (size_t)s2 * 256 + c16 * 4;
            const u16* r3 = m + (size_t)s3 * 256 + c16 * 4;
            #pragma unroll
            for (int tt = 0; tt < 4; ++tt) {
                H4 w0 = *(const H4*)(r0 + tt * 64);
                H4 w1 = *(const H4*)(r1 + tt * 64);
                H4 w2 = *(const H4*)(r2 + tt * 64);
                H4 w3 = *(const H4*)(r3 + tt * 64);
                acc[tt][0] = __hadd2(acc[tt][0], __hadd2(__hadd2(w0.a, w1.a), __hadd2(w2.a, w3.a)));
                acc[tt][1] = __hadd2(acc[tt][1], __hadd2(__hadd2(w0.b, w1.b), __hadd2(w2.b, w3.b)));
            }
        }
        // stage tt=0,1 into LDS now; defer tt=2,3 in registers
        #pragma unroll
        for (int tt = 0; tt < 2; ++tt) {
            float2 f01 = __half22float2(acc[tt][0]);
            float2 f23 = __half22float2(acc[tt][1]);
            u32 o0 = ((u32)f2b(f01.y * cdd[k]) << 16) | f2b(f01.x * cdd[k]);
            u32 o1 = ((u32)f2b(f23.y * cdd[k]) << 16) | f2b(f23.x * cdd[k]);
            u32* dstp = (u32*)(zw0 + tt * 1408 + j * 88 + c16 * 4);
            dstp[0] = o0; dstp[1] = o1;
        }
        def[k][0][0] = acc[2][0]; def[k][0][1] = acc[2][1];
        def[k][1][0] = acc[3][0]; def[k][1][1] = acc[3][1];
    }
    asm volatile("s_waitcnt lgkmcnt(0)" ::: "memory");   // wave-local zs ready

    // ---- two rounds: GEMMs for tt-pair {0,1}, then restage and do {2,3} ----
    #pragma unroll
    for (int half = 0; half < 2; ++half) {
        if (half == 1) {
            // all LDS reads of round 0 retired; overwrite regions with deferred tt=2,3
            asm volatile("s_waitcnt lgkmcnt(0)" ::: "memory");
            #pragma unroll
            for (int k = 0; k < 4; ++k) {
                int j = g16 * 4 + k;
                #pragma unroll
                for (int d = 0; d < 2; ++d) {
                    float2 f01 = __half22float2(def[k][d][0]);
                    float2 f23 = __half22float2(def[k][d][1]);
                    u32 o0 = ((u32)f2b(f01.y * cdd[k]) << 16) | f2b(f01.x * cdd[k]);
                    u32 o1 = ((u32)f2b(f23.y * cdd[k]) << 16) | f2b(f23.x * cdd[k]);
                    u32* dstp = (u32*)(zw0 + d * 1408 + j * 88 + c16 * 4);
                    dstp[0] = o0; dstp[1] = o1;
                }
            }
            asm volatile("s_waitcnt lgkmcnt(0)" ::: "memory");
        }
        #pragma unroll
        for (int d = 0; d < 2; ++d) {
            const int t = t0 + half * 2 + d;
            u16* zw = zw0 + d * 1408;
            const u16* ab = zw + c16 * 88 + g16 * 8;
            short8 a0 = *(const short8*)ab;            // A[m=c16][k=g16*8+j]
            short8 a1 = *(const short8*)(ab + 32);     // k += 32

            const u16* fw = fragWdec + (size_t)t * 4096;
            float4v C1[4];
            #pragma unroll
            for (int cc = 0; cc < 4; ++cc) {
                float4v z4 = {0.f, 0.f, 0.f, 0.f};
                short8 b0 = *(const short8*)(fw + (cc * 2 + 0) * 512 + lane * 8);
                short8 b1 = *(const short8*)(fw + (cc * 2 + 1) * 512 + lane * 8);
                z4 = __builtin_amdgcn_mfma_f32_16x16x32_bf16(a0, b0, z4, 0, 0, 0);
                C1[cc] = __builtin_amdgcn_mfma_f32_16x16x32_bf16(a1, b1, z4, 0, 0, 0);
            }

            float pw[4] = {0.f, 0.f, 0.f, 0.f};
            #pragma unroll
            for (int cc = 0; cc < 4; ++cc) {
                float bt = b_dec[t * 64 + cc * 16 + c16];
                float wo = W_o[cc * 16 + c16];
                #pragma unroll
                for (int r = 0; r < 4; ++r) {
                    float xx = C1[cc][r] + bt;            // C row(node)=g16*4+r, col=cc*16+c16
                    float sp = xx > 0.f ? xx : 0.01f * xx;
                    pw[r] = fmaf(sp, wo, pw[r]);
                    zw[(g16 * 4 + r) * 88 + cc * 16 + c16] = f2b(sp);
                }
            }
            asm volatile("s_waitcnt lgkmcnt(0)" ::: "memory");
            short8 sa0 = *(const short8*)ab;
            short8 sa1 = *(const short8*)(ab + 32);

            float4v C2[8];
            #pragma unroll
            for (int cc = 0; cc < 8; ++cc) {
                float4v z4 = {0.f, 0.f, 0.f, 0.f};
                short8 b0 = *(const short8*)(fragWa1 + (cc * 2 + 0) * 512 + lane * 8);
                short8 b1 = *(const short8*)(fragWa1 + (cc * 2 + 1) * 512 + lane * 8);
                z4 = __builtin_amdgcn_mfma_f32_16x16x32_bf16(sa0, b0, z4, 0, 0, 0);
                C2[cc] = __builtin_amdgcn_mfma_f32_16x16x32_bf16(sa1, b1, z4, 0, 0, 0);
            }

            float p1[4] = {0.f, 0.f, 0.f, 0.f};
            #pragma unroll
            for (int cc = 0; cc < 8; ++cc) {
                int k = cc * 16 + c16;
                float ba = b_a1[k], wa = W_a2[k];
                #pragma unroll
                for (int r = 0; r < 4; ++r)
                    p1[r] = fmaf(fast_tanh(C2[cc][r] + ba), wa, p1[r]);
            }

            #pragma unroll
            for (int mm = 1; mm < 16; mm <<= 1) {
                #pragma unroll
                for (int r = 0; r < 4; ++r) {
                    p1[r] += __shfl_xor(p1[r], mm);
                    pw[r] += __shfl_xor(pw[r], mm);
                }
            }

            if (c16 == 0) {
                #pragma unroll
                for (int r = 0; r < 4; ++r) {
                    int n = nw + g16 * 4 + r;
                    if (n < NF) {
                        S1[(size_t)t * NF + n] = p1[r];
                        PW[(size_t)t * NF + n] = pw[r];
                    }
                }
            }
        }
    }
}

// ---------------- 12-step scalar recurrence: 1 thread per node, table-lerp for s2 ----------------
__global__ __launch_bounds__(256) void dec_scan(
    const float* __restrict__ S1, const float* __restrict__ PW,
    const float* __restrict__ gtab, const float* __restrict__ uvs,
    const float* __restrict__ feat, const float* __restrict__ b_a2p,
    const float* __restrict__ b_op, float* __restrict__ out) {
    const int n = blockIdx.x * 256 + threadIdx.x;
    if (n >= NF) return;
    float s1v[12], pwv[12];
    #pragma unroll
    for (int t = 0; t < 12; ++t) {
        s1v[t] = S1[(size_t)t * NF + n];
        pwv[t] = PW[(size_t)t * NF + n];
    }
    const float wlo = uvs[256], blo = uvs[257], ba2 = b_a2p[0], bo = b_op[0];
    float yp = feat[n * 12 + 11];
    yp = (yp != yp) ? 0.f : yp;
    #pragma unroll
    for (int t = 0; t < 12; ++t) {
        float xf = fminf(fmaxf(fmaf(yp, 256.f, 8192.f), 0.f), 16383.f);
        int idx = (int)xf;
        float fr = xf - (float)idx;
        float g0 = gtab[idx], g1 = gtab[idx + 1];
        float p2 = fmaf(g1 - g0, fr, g0);
        float s1s = s1v[t] + ba2, s2s = p2 + ba2;
        float mx = fmaxf(s1s, s2s);
        float e1 = __expf(s1s - mx), e2 = __expf(s2s - mx);
        float y = (e1 * pwv[t] + e2 * fmaf(wlo, yp, blo)) / (e1 + e2) + bo;
        out[(size_t)t * NF + n] = y;
        yp = y;
    }
}

// ---------------- launch ----------------
extern "C" void kernel_launch(void* const* d_in, const int* in_sizes, int n_in,
                              void* d_out, int out_size, void* d_ws, size_t ws_size,
                              hipStream_t stream) {
    const float* feat   = (const float*)d_in[0];
    const int* enc_src  = (const int*)d_in[1];
    const int* enc_dst  = (const int*)d_in[2];
    const int* dec_src  = (const int*)d_in[3];
    const int* dec_dst  = (const int*)d_in[4];
    const float* W_enc  = (const float*)d_in[5];
    const float* b_enc  = (const float*)d_in[6];
    const float* W_proc = (const float*)d_in[7];
    const float* b_proc = (const float*)d_in[8];
    const float* W_dec  = (const float*)d_in[9];
    const float* b_dec  = (const float*)d_in[10];
    const float* W_lin  = (const float*)d_in[11];
    const float* b_lin  = (const float*)d_in[12];
    const float* W_a1   = (const float*)d_in[13];
    const float* b_a1   = (const float*)d_in[14];
    const float* W_a2   = (const float*)d_in[15];
    const float* b_a2   = (const float*)d_in[16];
    const float* W_o    = (const float*)d_in[17];
    const float* b_o    = (const float*)d_in[18];
    float* out = (float*)d_out;

    float* W = (float*)d_ws;
    float* deg_se   = W;                       // NF                 0 .. 100000
    float* deg_sd   = W + 100000;              // NH                 .. 149152
    int*   cntD     = (int*)(W + 149152);      // NF                 .. 249152
    int*   cntE     = (int*)(W + 249152);      // NH                 .. 298304
    float* uvs      = W + 298304;              // 260 -> pad 298624
    u16*   fragWdec = (u16*)(W + 298624);      // 49152 u16          .. 323200
    u16*   fragWa1  = (u16*)(W + 323200);      // 8192 u16           .. 327296
    float* agg      = W + 327296;              // NH*16              .. 1113728
    float* S1       = W + 1113728;             // 12*NF              .. 2313728
    float* PW       = W + 2313728;             // 12*NF              .. 3513728
    u16*   csrD     = (u16*)(W + 3513728);     // NF*24 u16          .. 4713728
    u32*   csrE     = (u32*)(W + 4713728);     // NH*32              .. 6286592
    u16*   m_chunk  = (u16*)(W + 6286592);     // (NH+1)*256 u16     .. 12578176
    float* gtab     = W + 12578176;            // 16385 -> end 12594561 (~50.4 MB)

    const int PTOT = PN1 + PN2 + PN3 + PN4;
    prefill<<<(PTOT + 255) / 256, 256, 0, stream>>>((u32*)csrD, csrE, (u32*)W,
                                                    (u32*)(m_chunk + (size_t)NH * 256));
    fill_slotted<<<(EDG + 255) / 256, 256, 0, stream>>>(enc_src, enc_dst, dec_src, dec_dst,
                                                        cntD, csrD, deg_sd, cntE, csrE, deg_se);
    prep_small<<<29, 256, 0, stream>>>(W_dec, W_a1, fragWdec, fragWa1,
                                       W_lin, b_lin, b_a1, W_o, uvs);
    build_gtab<<<65, 256, 0, stream>>>(uvs, W_a2, gtab);
    enc_gather<<<NH / 64, 256, 0, stream>>>(feat, deg_se, cntE, csrE, agg);

    const int dec_grid = (NF + 63) / 64;
    for (int c = 0; c < 3; ++c) {
        make_chunk<<<(NH * 64) / 256, 256, 0, stream>>>(agg, cntE, deg_sd, W_enc, b_enc,
                                                        W_proc, b_proc, m_chunk, 4 * c);
        dec_batch<<<dec_grid, 256, 0, stream>>>(m_chunk, cntD, csrD, fragWdec, fragWa1,
                                                b_dec, b_a1, W_a2, W_o, S1, PW, 4 * c);
    }
    dec_scan<<<(NF + 255) / 256, 256, 0, stream>>>(S1, PW, gtab, uvs, feat, b_a2, b_o, out);
}

// Round 11
// 494.762 us; speedup vs baseline: 1.0759x; 1.0759x over previous
//
#include <hip/hip_runtime.h>
#include <hip/hip_bf16.h>
#include <hip/hip_fp16.h>

#define NF 100000
#define NH 49152
#define EDG 400000
#define SLOTD 24
#define SLOTE 32

typedef __attribute__((ext_vector_type(8))) short short8;
typedef __attribute__((ext_vector_type(4))) float float4v;
typedef unsigned short u16;
typedef unsigned int u32;

__device__ __forceinline__ u16 f2b(float x) {
    u32 u = __float_as_uint(x);
    u32 r = u + 0x7FFFu + ((u >> 16) & 1u);
    return (u16)(r >> 16);
}
__device__ __forceinline__ __half2 h2(u32 v) { union { u32 u; __half2 h; } c; c.u = v; return c.h; }
__device__ __forceinline__ float fast_tanh(float x) {
    float ex = __expf(2.0f * x);
    return 1.0f - 2.0f / (ex + 1.0f);
}

// ---------------- one-kernel init: csrD sentinel, csrE zeros, deg/cnt zeros, m zero row ----------------
#define PN1 (NF * 12)            /* csrD as u32: NF*24/2 */
#define PN2 (NH * SLOTE)         /* csrE u32 */
#define PN3 298304               /* deg_se,deg_sd,cntD,cntE */
#define PN4 128                  /* m zero row as u32 */
__global__ void prefill(u32* __restrict__ csrD32, u32* __restrict__ csrE,
                        u32* __restrict__ degcnt, u32* __restrict__ mzero) {
    int i = blockIdx.x * 256 + threadIdx.x;
    if (i < PN1) csrD32[i] = ((u32)NH << 16) | (u32)NH;
    else if (i < PN1 + PN2) csrE[i - PN1] = 0u;
    else if (i < PN1 + PN2 + PN3) degcnt[i - PN1 - PN2] = 0u;
    else if (i < PN1 + PN2 + PN3 + PN4) mzero[i - PN1 - PN2 - PN3] = 0u;
}

// ---------------- one-pass slotted CSR build (both graphs) + src-degree counts ----------------
__global__ void fill_slotted(const int* __restrict__ enc_src, const int* __restrict__ enc_dst,
                             const int* __restrict__ dec_src, const int* __restrict__ dec_dst,
                             int* __restrict__ cntD, u16* __restrict__ csrD, float* __restrict__ deg_sd,
                             int* __restrict__ cntE, u32* __restrict__ csrE, float* __restrict__ deg_se) {
    int e = blockIdx.x * 256 + threadIdx.x;
    if (e >= EDG) return;
    int ds = dec_src[e], dd = dec_dst[e];
    int i1 = atomicAdd(&cntD[dd], 1);
    if (i1 < SLOTD) csrD[(size_t)dd * SLOTD + i1] = (u16)ds;   // dec_src < NH < 65536
    atomicAdd(&deg_sd[ds], 1.0f);
    int es = enc_src[e], ed = enc_dst[e];
    int i2 = atomicAdd(&cntE[ed], 1);
    if (i2 < SLOTE) csrE[(size_t)ed * SLOTE + i2] = (u32)es;
    atomicAdd(&deg_se[es], 1.0f);
}

// ---------------- bf16 B-fragment prep + uv prep (blocks 0..27 frag, 28 uv) ----------------
__global__ void prep_small(const float* __restrict__ W_dec, const float* __restrict__ W_a1,
                           u16* __restrict__ fragWdec, u16* __restrict__ fragWa1,
                           const float* __restrict__ W_lin, const float* __restrict__ b_lin,
                           const float* __restrict__ b_a1, const float* __restrict__ W_o,
                           float* __restrict__ uvs) {
    const int b = blockIdx.x;
    if (b < 28) {
        int gid = b * 256 + threadIdx.x;   // 0..7167
        if (gid >= 7168) return;
        int L = gid & 63;
        int f = gid >> 6;          // 0..95: W_dec (t=f>>3); 96..111: W_a1
        int q = L >> 4, cb = L & 15;
        if (f < 96) {
            int fr = f & 7;
            int c = fr >> 1, kc = fr & 1;
            int k0 = kc * 32 + q * 8;
            int nn = c * 16 + cb;
            int t = f >> 3;
            #pragma unroll
            for (int j = 0; j < 8; ++j)
                fragWdec[(f * 64 + L) * 8 + j] = f2b(W_dec[t * 4096 + (k0 + j) * 64 + nn]);
        } else {
            int fr = f - 96;
            int c2 = fr >> 1, kc = fr & 1;
            int k0 = kc * 32 + q * 8;
            int nn = c2 * 16 + cb;
            #pragma unroll
            for (int j = 0; j < 8; ++j)
                fragWa1[(fr * 64 + L) * 8 + j] = f2b(W_a1[(k0 + j) * 128 + nn]);
        }
    } else {
        int k = threadIdx.x;
        if (k < 128) {
            float su = 0.f, sv = 0.f;
            for (int h = 0; h < 64; ++h) {
                su = fmaf(W_lin[h], W_a1[h * 128 + k], su);
                sv = fmaf(b_lin[h], W_a1[h * 128 + k], sv);
            }
            uvs[k] = su;
            uvs[128 + k] = sv + b_a1[k];
            if (k == 0) {
                float a = 0.f, bb = 0.f;
                for (int h = 0; h < 64; ++h) {
                    a = fmaf(W_lin[h], W_o[h], a);
                    bb = fmaf(b_lin[h], W_o[h], bb);
                }
                uvs[256] = a;  // wlo
                uvs[257] = bb; // blo
            }
        }
    }
}

// ---------------- tabulate g(y) = sum_k tanh(y*u_k + v_k) * w_k over y in [-32,32] ----------------
__global__ void build_gtab(const float* __restrict__ uvs, const float* __restrict__ W_a2,
                           float* __restrict__ gtab) {
    int i = blockIdx.x * 256 + threadIdx.x;
    if (i > 16384) return;
    float y = fmaf((float)i, 1.f / 256.f, -32.f);
    float s = 0.f;
    for (int k = 0; k < 128; ++k)
        s = fmaf(fast_tanh(fmaf(y, uvs[k], uvs[128 + k])), W_a2[k], s);
    gtab[i] = s;
}

// ---------------- encoder aggregation: agg[dst][0..15] = sum nan_to_num(feat[src])*c_se[src] ----------
__global__ __launch_bounds__(256) void enc_gather(const float* __restrict__ feat,
                                                  const float* __restrict__ deg_se,
                                                  const int* __restrict__ cntE,
                                                  const u32* __restrict__ csrE,
                                                  float* __restrict__ agg) {
    const int tid = threadIdx.x, lane = tid & 63, wid = tid >> 6;
    const int grp = lane >> 2, l = lane & 3;      // 16 quads of 4 lanes
    const int dst = blockIdx.x * 64 + wid * 16 + grp;
    int cnt = cntE[dst];
    if (cnt > SLOTE) cnt = SLOTE;
    const u32* cp = csrE + (size_t)dst * SLOTE;
    float4 a = {0.f, 0.f, 0.f, 0.f};
    if (l < 3) {
        for (int e = 0; e < cnt; e += 4) {
            u32 s0 = cp[e], s1 = cp[e + 1], s2 = cp[e + 2], s3 = cp[e + 3];
            float c0 = rsqrtf(fmaxf(deg_se[s0], 1.0f));
            float c1 = (e + 1 < cnt) ? rsqrtf(fmaxf(deg_se[s1], 1.0f)) : 0.f;
            float c2 = (e + 2 < cnt) ? rsqrtf(fmaxf(deg_se[s2], 1.0f)) : 0.f;
            float c3 = (e + 3 < cnt) ? rsqrtf(fmaxf(deg_se[s3], 1.0f)) : 0.f;
            float4 w0 = *(const float4*)(feat + (size_t)s0 * 12 + l * 4);
            float4 w1 = *(const float4*)(feat + (size_t)s1 * 12 + l * 4);
            float4 w2 = *(const float4*)(feat + (size_t)s2 * 12 + l * 4);
            float4 w3 = *(const float4*)(feat + (size_t)s3 * 12 + l * 4);
            w0.x = (w0.x != w0.x) ? 0.f : w0.x; w0.y = (w0.y != w0.y) ? 0.f : w0.y;
            w0.z = (w0.z != w0.z) ? 0.f : w0.z; w0.w = (w0.w != w0.w) ? 0.f : w0.w;
            w1.x = (w1.x != w1.x) ? 0.f : w1.x; w1.y = (w1.y != w1.y) ? 0.f : w1.y;
            w1.z = (w1.z != w1.z) ? 0.f : w1.z; w1.w = (w1.w != w1.w) ? 0.f : w1.w;
            w2.x = (w2.x != w2.x) ? 0.f : w2.x; w2.y = (w2.y != w2.y) ? 0.f : w2.y;
            w2.z = (w2.z != w2.z) ? 0.f : w2.z; w2.w = (w2.w != w2.w) ? 0.f : w2.w;
            w3.x = (w3.x != w3.x) ? 0.f : w3.x; w3.y = (w3.y != w3.y) ? 0.f : w3.y;
            w3.z = (w3.z != w3.z) ? 0.f : w3.z; w3.w = (w3.w != w3.w) ? 0.f : w3.w;
            a.x = fmaf(w0.x, c0, fmaf(w1.x, c1, fmaf(w2.x, c2, fmaf(w3.x, c3, a.x))));
            a.y = fmaf(w0.y, c0, fmaf(w1.y, c1, fmaf(w2.y, c2, fmaf(w3.y, c3, a.y))));
            a.z = fmaf(w0.z, c0, fmaf(w1.z, c1, fmaf(w2.z, c2, fmaf(w3.z, c3, a.z))));
            a.w = fmaf(w0.w, c0, fmaf(w1.w, c1, fmaf(w2.w, c2, fmaf(w3.w, c3, a.w))));
        }
    }
    *(float4*)(agg + (size_t)dst * 16 + l * 4) = a;   // l==3 writes zero pad
}

// ---------------- m chunk (node-major, FP16, tt-minor): m[n][h][tt] for t = t0..t0+3 ----------------
__global__ void make_chunk(const float* __restrict__ agg, const int* __restrict__ cntE,
                           const float* __restrict__ deg_sd, const float* __restrict__ W_enc,
                           const float* __restrict__ b_enc, const float* __restrict__ W_proc,
                           const float* __restrict__ b_proc, u16* __restrict__ m, int t0) {
    int gid = blockIdx.x * 256 + threadIdx.x;
    if (gid >= NH * 64) return;
    int n = gid >> 6, h = gid & 63;
    float cde = rsqrtf(fmaxf((float)cntE[n], 1.0f));
    float csd = rsqrtf(fmaxf(deg_sd[n], 1.0f));
    float he[12];
    #pragma unroll
    for (int ti = 0; ti < 12; ++ti) {
        float a = agg[n * 16 + ti] * cde;
        float x = fmaf(a, W_enc[ti * 64 + h], b_enc[ti * 64 + h]);
        he[ti] = x > 0.f ? x : 0.01f * x;
    }
    u16 r[4];
    #pragma unroll
    for (int tt = 0; tt < 4; ++tt) {
        int t = t0 + tt;
        float s = b_proc[t];
        #pragma unroll
        for (int ti = 0; ti < 12; ++ti) s = fmaf(he[ti], W_proc[ti * 12 + t], s);
        s = fmaxf(s, 0.f) * csd;
        r[tt] = __half_as_ushort(__float2half(s));
    }
    u32 o0 = ((u32)r[1] << 16) | r[0];
    u32 o1 = ((u32)r[3] << 16) | r[2];
    u32* dst = (u32*)(m + (size_t)n * 256 + h * 4);
    dst[0] = o0; dst[1] = o1;
}

// ---------------- decoder chunk pass: MLP-maximized gather + MFMA GEMMs ----------------
__global__ __launch_bounds__(256) void dec_batch(
    const u16* __restrict__ m, const int* __restrict__ cntD, const u16* __restrict__ csrD,
    const u16* __restrict__ fragWdec, const u16* __restrict__ fragWa1,
    const float* __restrict__ b_dec, const float* __restrict__ b_a1,
    const float* __restrict__ W_a2, const float* __restrict__ W_o,
    float* __restrict__ S1, float* __restrict__ PW, int t0) {
    __shared__ __align__(16) u16 zs[22528];   // 4 waves x (4 tt x 16 rows x 88)

    const int tid = threadIdx.x, lane = tid & 63, wid = tid >> 6;
    const int nw = blockIdx.x * 64 + wid * 16;
    const int g16 = lane >> 4, c16 = lane & 15;
    u16* zw0 = zs + wid * 5632;

    // ---- hoisted per-node metadata + full csr rows (all independent loads) ----
    int cdw[4]; float cdd[4];
    uint4 q[4][3];
    #pragma unroll
    for (int k = 0; k < 4; ++k) {
        int n = nw + g16 * 4 + k;
        bool v = (n < NF);
        int nn = v ? n : 0;
        int cd = cntD[nn];
        cdd[k] = v ? rsqrtf(fmaxf((float)cd, 1.0f)) : 0.f;
        cdw[k] = v ? (cd > SLOTD ? SLOTD : cd) : 0;
        const uint4* cp4 = (const uint4*)(csrD + (size_t)nn * SLOTD);
        q[k][0] = cp4[0]; q[k][1] = cp4[1]; q[k][2] = cp4[2];
    }

    // acc[k][ch*2 + p]: node k, channel c16*4+ch, tt-pair p ({tt0,tt1} / {tt2,tt3})
    __half2 acc[4][8];
    #pragma unroll
    for (int k = 0; k < 4; ++k)
        #pragma unroll
        for (int i = 0; i < 8; ++i)
            acc[k][i] = __half2{__half(0.f), __half(0.f)};

    const u16* mrow = m + c16 * 16;
    #pragma unroll
    for (int it = 0; it < 6; ++it) {
        #pragma unroll
        for (int k = 0; k < 4; ++k) {
            if (it * 4 < cdw[k]) {
                u32 lo = (it & 1) ? q[k][it >> 1].z : q[k][it >> 1].x;
                u32 hi = (it & 1) ? q[k][it >> 1].w : q[k][it >> 1].y;
                int s0 = (int)(lo & 0xFFFF), s1 = (int)(lo >> 16);
                int s2 = (int)(hi & 0xFFFF), s3 = (int)(hi >> 16);
                const uint4* r0 = (const uint4*)(mrow + (size_t)s0 * 256);
                const uint4* r1 = (const uint4*)(mrow + (size_t)s1 * 256);
                const uint4* r2 = (const uint4*)(mrow + (size_t)s2 * 256);
                const uint4* r3 = (const uint4*)(mrow + (size_t)s3 * 256);
                uint4 A0 = r0[0], B0 = r0[1];
                uint4 A1 = r1[0], B1 = r1[1];
                uint4 A2 = r2[0], B2 = r2[1];
                uint4 A3 = r3[0], B3 = r3[1];
                acc[k][0] = __hadd2(acc[k][0], __hadd2(__hadd2(h2(A0.x), h2(A1.x)), __hadd2(h2(A2.x), h2(A3.x))));
                acc[k][1] = __hadd2(acc[k][1], __hadd2(__hadd2(h2(A0.y), h2(A1.y)), __hadd2(h2(A2.y), h2(A3.y))));
                acc[k][2] = __hadd2(acc[k][2], __hadd2(__hadd2(h2(A0.z), h2(A1.z)), __hadd2(h2(A2.z), h2(A3.z))));
                acc[k][3] = __hadd2(acc[k][3], __hadd2(__hadd2(h2(A0.w), h2(A1.w)), __hadd2(h2(A2.w), h2(A3.w))));
                acc[k][4] = __hadd2(acc[k][4], __hadd2(__hadd2(h2(B0.x), h2(B1.x)), __hadd2(h2(B2.x), h2(B3.x))));
                acc[k][5] = __hadd2(acc[k][5], __hadd2(__hadd2(h2(B0.y), h2(B1.y)), __hadd2(h2(B2.y), h2(B3.y))));
                acc[k][6] = __hadd2(acc[k][6], __hadd2(__hadd2(h2(B0.z), h2(B1.z)), __hadd2(h2(B2.z), h2(B3.z))));
                acc[k][7] = __hadd2(acc[k][7], __hadd2(__hadd2(h2(B0.w), h2(B1.w)), __hadd2(h2(B2.w), h2(B3.w))));
            }
        }
    }

    // ---- stage all 4 tt into LDS (A-operand layout per tt) ----
    #pragma unroll
    for (int k = 0; k < 4; ++k) {
        int j = g16 * 4 + k;
        float s = cdd[k];
        #pragma unroll
        for (int p = 0; p < 2; ++p) {
            float2 c0 = __half22float2(acc[k][0 * 2 + p]);
            float2 c1 = __half22float2(acc[k][1 * 2 + p]);
            float2 c2 = __half22float2(acc[k][2 * 2 + p]);
            float2 c3 = __half22float2(acc[k][3 * 2 + p]);
            u32 oA0 = ((u32)f2b(c1.x * s) << 16) | f2b(c0.x * s);
            u32 oA1 = ((u32)f2b(c3.x * s) << 16) | f2b(c2.x * s);
            u32 oB0 = ((u32)f2b(c1.y * s) << 16) | f2b(c0.y * s);
            u32 oB1 = ((u32)f2b(c3.y * s) << 16) | f2b(c2.y * s);
            u32* dA = (u32*)(zw0 + (2 * p) * 1408 + j * 88 + c16 * 4);
            u32* dB = (u32*)(zw0 + (2 * p + 1) * 1408 + j * 88 + c16 * 4);
            dA[0] = oA0; dA[1] = oA1;
            dB[0] = oB0; dB[1] = oB1;
        }
    }
    asm volatile("s_waitcnt lgkmcnt(0)" ::: "memory");   // wave-local zs ready

    // ---- per-t GEMM pipeline (B-fragments streamed from L2; no __syncthreads) ----
    for (int tt = 0; tt < 4; ++tt) {
        const int t = t0 + tt;
        u16* zw = zw0 + tt * 1408;
        const u16* ab = zw + c16 * 88 + g16 * 8;
        short8 a0 = *(const short8*)ab;            // A[m=c16][k=g16*8+j]
        short8 a1 = *(const short8*)(ab + 32);     // k += 32

        const u16* fw = fragWdec + (size_t)t * 4096;
        float4v C1[4];
        #pragma unroll
        for (int cc = 0; cc < 4; ++cc) {
            float4v z4 = {0.f, 0.f, 0.f, 0.f};
            short8 b0 = *(const short8*)(fw + (cc * 2 + 0) * 512 + lane * 8);
            short8 b1 = *(const short8*)(fw + (cc * 2 + 1) * 512 + lane * 8);
            z4 = __builtin_amdgcn_mfma_f32_16x16x32_bf16(a0, b0, z4, 0, 0, 0);
            C1[cc] = __builtin_amdgcn_mfma_f32_16x16x32_bf16(a1, b1, z4, 0, 0, 0);
        }

        float pw[4] = {0.f, 0.f, 0.f, 0.f};
        #pragma unroll
        for (int cc = 0; cc < 4; ++cc) {
            float bt = b_dec[t * 64 + cc * 16 + c16];
            float wo = W_o[cc * 16 + c16];
            #pragma unroll
            for (int r = 0; r < 4; ++r) {
                float xx = C1[cc][r] + bt;            // C row(node)=g16*4+r, col=cc*16+c16
                float sp = xx > 0.f ? xx : 0.01f * xx;
                pw[r] = fmaf(sp, wo, pw[r]);
                zw[(g16 * 4 + r) * 88 + cc * 16 + c16] = f2b(sp);
            }
        }
        asm volatile("s_waitcnt lgkmcnt(0)" ::: "memory");
        short8 sa0 = *(const short8*)ab;
        short8 sa1 = *(const short8*)(ab + 32);

        float4v C2[8];
        #pragma unroll
        for (int cc = 0; cc < 8; ++cc) {
            float4v z4 = {0.f, 0.f, 0.f, 0.f};
            short8 b0 = *(const short8*)(fragWa1 + (cc * 2 + 0) * 512 + lane * 8);
            short8 b1 = *(const short8*)(fragWa1 + (cc * 2 + 1) * 512 + lane * 8);
            z4 = __builtin_amdgcn_mfma_f32_16x16x32_bf16(sa0, b0, z4, 0, 0, 0);
            C2[cc] = __builtin_amdgcn_mfma_f32_16x16x32_bf16(sa1, b1, z4, 0, 0, 0);
        }

        float p1[4] = {0.f, 0.f, 0.f, 0.f};
        #pragma unroll
        for (int cc = 0; cc < 8; ++cc) {
            int k = cc * 16 + c16;
            float ba = b_a1[k], wa = W_a2[k];
            #pragma unroll
            for (int r = 0; r < 4; ++r)
                p1[r] = fmaf(fast_tanh(C2[cc][r] + ba), wa, p1[r]);
        }

        #pragma unroll
        for (int mm = 1; mm < 16; mm <<= 1) {
            #pragma unroll
            for (int r = 0; r < 4; ++r) {
                p1[r] += __shfl_xor(p1[r], mm);
                pw[r] += __shfl_xor(pw[r], mm);
            }
        }

        if (c16 == 0) {
            #pragma unroll
            for (int r = 0; r < 4; ++r) {
                int n = nw + g16 * 4 + r;
                if (n < NF) {
                    S1[(size_t)t * NF + n] = p1[r];
                    PW[(size_t)t * NF + n] = pw[r];
                }
            }
        }
    }
}

// ---------------- 12-step scalar recurrence: 1 thread per node, table-lerp for s2 ----------------
__global__ __launch_bounds__(256) void dec_scan(
    const float* __restrict__ S1, const float* __restrict__ PW,
    const float* __restrict__ gtab, const float* __restrict__ uvs,
    const float* __restrict__ feat, const float* __restrict__ b_a2p,
    const float* __restrict__ b_op, float* __restrict__ out) {
    const int n = blockIdx.x * 256 + threadIdx.x;
    if (n >= NF) return;
    float s1v[12], pwv[12];
    #pragma unroll
    for (int t = 0; t < 12; ++t) {
        s1v[t] = S1[(size_t)t * NF + n];
        pwv[t] = PW[(size_t)t * NF + n];
    }
    const float wlo = uvs[256], blo = uvs[257], ba2 = b_a2p[0], bo = b_op[0];
    float yp = feat[n * 12 + 11];
    yp = (yp != yp) ? 0.f : yp;
    #pragma unroll
    for (int t = 0; t < 12; ++t) {
        float xf = fminf(fmaxf(fmaf(yp, 256.f, 8192.f), 0.f), 16383.f);
        int idx = (int)xf;
        float fr = xf - (float)idx;
        float g0 = gtab[idx], g1 = gtab[idx + 1];
        float p2 = fmaf(g1 - g0, fr, g0);
        float s1s = s1v[t] + ba2, s2s = p2 + ba2;
        float mx = fmaxf(s1s, s2s);
        float e1 = __expf(s1s - mx), e2 = __expf(s2s - mx);
        float y = (e1 * pwv[t] + e2 * fmaf(wlo, yp, blo)) / (e1 + e2) + bo;
        out[(size_t)t * NF + n] = y;
        yp = y;
    }
}

// ---------------- launch ----------------
extern "C" void kernel_launch(void* const* d_in, const int* in_sizes, int n_in,
                              void* d_out, int out_size, void* d_ws, size_t ws_size,
                              hipStream_t stream) {
    const float* feat   = (const float*)d_in[0];
    const int* enc_src  = (const int*)d_in[1];
    const int* enc_dst  = (const int*)d_in[2];
    const int* dec_src  = (const int*)d_in[3];
    const int* dec_dst  = (const int*)d_in[4];
    const float* W_enc  = (const float*)d_in[5];
    const float* b_enc  = (const float*)d_in[6];
    const float* W_proc = (const float*)d_in[7];
    const float* b_proc = (const float*)d_in[8];
    const float* W_dec  = (const float*)d_in[9];
    const float* b_dec  = (const float*)d_in[10];
    const float* W_lin  = (const float*)d_in[11];
    const float* b_lin  = (const float*)d_in[12];
    const float* W_a1   = (const float*)d_in[13];
    const float* b_a1   = (const float*)d_in[14];
    const float* W_a2   = (const float*)d_in[15];
    const float* b_a2   = (const float*)d_in[16];
    const float* W_o    = (const float*)d_in[17];
    const float* b_o    = (const float*)d_in[18];
    float* out = (float*)d_out;

    float* W = (float*)d_ws;
    float* deg_se   = W;                       // NF                 0 .. 100000
    float* deg_sd   = W + 100000;              // NH                 .. 149152
    int*   cntD     = (int*)(W + 149152);      // NF                 .. 249152
    int*   cntE     = (int*)(W + 249152);      // NH                 .. 298304
    float* uvs      = W + 298304;              // 260 -> pad 298624
    u16*   fragWdec = (u16*)(W + 298624);      // 49152 u16          .. 323200
    u16*   fragWa1  = (u16*)(W + 323200);      // 8192 u16           .. 327296
    float* agg      = W + 327296;              // NH*16              .. 1113728
    float* S1       = W + 1113728;             // 12*NF              .. 2313728
    float* PW       = W + 2313728;             // 12*NF              .. 3513728
    u16*   csrD     = (u16*)(W + 3513728);     // NF*24 u16          .. 4713728
    u32*   csrE     = (u32*)(W + 4713728);     // NH*32              .. 6286592
    u16*   m_chunk  = (u16*)(W + 6286592);     // (NH+1)*256 u16     .. 12578176
    float* gtab     = W + 12578176;            // 16385 -> end 12594561 (~50.4 MB)

    const int PTOT = PN1 + PN2 + PN3 + PN4;
    prefill<<<(PTOT + 255) / 256, 256, 0, stream>>>((u32*)csrD, csrE, (u32*)W,
                                                    (u32*)(m_chunk + (size_t)NH * 256));
    fill_slotted<<<(EDG + 255) / 256, 256, 0, stream>>>(enc_src, enc_dst, dec_src, dec_dst,
                                                        cntD, csrD, deg_sd, cntE, csrE, deg_se);
    prep_small<<<29, 256, 0, stream>>>(W_dec, W_a1, fragWdec, fragWa1,
                                       W_lin, b_lin, b_a1, W_o, uvs);
    build_gtab<<<65, 256, 0, stream>>>(uvs, W_a2, gtab);
    enc_gather<<<NH / 64, 256, 0, stream>>>(feat, deg_se, cntE, csrE, agg);

    const int dec_grid = (NF + 63) / 64;
    for (int c = 0; c < 3; ++c) {
        make_chunk<<<(NH * 64) / 256, 256, 0, stream>>>(agg, cntE, deg_sd, W_enc, b_enc,
                                                        W_proc, b_proc, m_chunk, 4 * c);
        dec_batch<<<dec_grid, 256, 0, stream>>>(m_chunk, cntD, csrD, fragWdec, fragWa1,
                                                b_dec, b_a1, W_a2, W_o, S1, PW, 4 * c);
    }
    dec_scan<<<(NF + 255) / 256, 256, 0, stream>>>(S1, PW, gtab, uvs, feat, b_a2, b_o, out);
}

// Round 12
// 421.412 us; speedup vs baseline: 1.2632x; 1.1741x over previous
//
#include <hip/hip_runtime.h>
#include <hip/hip_bf16.h>
#include <hip/hip_fp16.h>

#define NF 100000
#define NH 49152
#define EDG 400000
#define SLOTD 24
#define SLOTE 32

typedef __attribute__((ext_vector_type(8))) short short8;
typedef __attribute__((ext_vector_type(4))) float float4v;
typedef unsigned short u16;
typedef unsigned int u32;

__device__ __forceinline__ u16 f2b(float x) {
    u32 u = __float_as_uint(x);
    u32 r = u + 0x7FFFu + ((u >> 16) & 1u);
    return (u16)(r >> 16);
}
__device__ __forceinline__ __half2 h2(u32 v) { union { u32 u; __half2 h; } c; c.u = v; return c.h; }
__device__ __forceinline__ float fast_tanh(float x) {
    float ex = __expf(2.0f * x);
    return 1.0f - 2.0f / (ex + 1.0f);
}

// ---------------- one-kernel init: csrD sentinel, csrE zeros, deg/cnt zeros, m zero rows ----------------
#define PN1 (NF * 12)            /* csrD as u32: NF*24/2 */
#define PN2 (NH * SLOTE)         /* csrE u32 */
#define PN3 298304               /* deg_se,deg_sd,cntD,cntE */
#define PN4 384                  /* 3 chunk zero rows as u32 (128 each) */
__global__ void prefill(u32* __restrict__ csrD32, u32* __restrict__ csrE,
                        u32* __restrict__ degcnt, u32* __restrict__ mzero, int zstride) {
    int i = blockIdx.x * 256 + threadIdx.x;
    if (i < PN1) csrD32[i] = ((u32)NH << 16) | (u32)NH;
    else if (i < PN1 + PN2) csrE[i - PN1] = 0u;
    else if (i < PN1 + PN2 + PN3) degcnt[i - PN1 - PN2] = 0u;
    else if (i < PN1 + PN2 + PN3 + PN4) {
        int j = i - PN1 - PN2 - PN3;
        mzero[(j >> 7) * (size_t)zstride + (j & 127)] = 0u;
    }
}

// ---------------- one-pass slotted CSR build (both graphs) + src-degree counts ----------------
__global__ void fill_slotted(const int* __restrict__ enc_src, const int* __restrict__ enc_dst,
                             const int* __restrict__ dec_src, const int* __restrict__ dec_dst,
                             int* __restrict__ cntD, u16* __restrict__ csrD, float* __restrict__ deg_sd,
                             int* __restrict__ cntE, u32* __restrict__ csrE, float* __restrict__ deg_se) {
    int e = blockIdx.x * 256 + threadIdx.x;
    if (e >= EDG) return;
    int ds = dec_src[e], dd = dec_dst[e];
    int i1 = atomicAdd(&cntD[dd], 1);
    if (i1 < SLOTD) csrD[(size_t)dd * SLOTD + i1] = (u16)ds;   // dec_src < NH < 65536
    atomicAdd(&deg_sd[ds], 1.0f);
    int es = enc_src[e], ed = enc_dst[e];
    int i2 = atomicAdd(&cntE[ed], 1);
    if (i2 < SLOTE) csrE[(size_t)ed * SLOTE + i2] = (u32)es;
    atomicAdd(&deg_se[es], 1.0f);
}

// ---------------- bf16 B-fragment prep + uv prep (blocks 0..27 frag, 28 uv) ----------------
__global__ void prep_small(const float* __restrict__ W_dec, const float* __restrict__ W_a1,
                           u16* __restrict__ fragWdec, u16* __restrict__ fragWa1,
                           const float* __restrict__ W_lin, const float* __restrict__ b_lin,
                           const float* __restrict__ b_a1, const float* __restrict__ W_o,
                           float* __restrict__ uvs) {
    const int b = blockIdx.x;
    if (b < 28) {
        int gid = b * 256 + threadIdx.x;   // 0..7167
        if (gid >= 7168) return;
        int L = gid & 63;
        int f = gid >> 6;          // 0..95: W_dec (t=f>>3); 96..111: W_a1
        int q = L >> 4, cb = L & 15;
        if (f < 96) {
            int fr = f & 7;
            int c = fr >> 1, kc = fr & 1;
            int k0 = kc * 32 + q * 8;
            int nn = c * 16 + cb;
            int t = f >> 3;
            #pragma unroll
            for (int j = 0; j < 8; ++j)
                fragWdec[(f * 64 + L) * 8 + j] = f2b(W_dec[t * 4096 + (k0 + j) * 64 + nn]);
        } else {
            int fr = f - 96;
            int c2 = fr >> 1, kc = fr & 1;
            int k0 = kc * 32 + q * 8;
            int nn = c2 * 16 + cb;
            #pragma unroll
            for (int j = 0; j < 8; ++j)
                fragWa1[(fr * 64 + L) * 8 + j] = f2b(W_a1[(k0 + j) * 128 + nn]);
        }
    } else {
        int k = threadIdx.x;
        if (k < 128) {
            float su = 0.f, sv = 0.f;
            for (int h = 0; h < 64; ++h) {
                su = fmaf(W_lin[h], W_a1[h * 128 + k], su);
                sv = fmaf(b_lin[h], W_a1[h * 128 + k], sv);
            }
            uvs[k] = su;
            uvs[128 + k] = sv + b_a1[k];
            if (k == 0) {
                float a = 0.f, bb = 0.f;
                for (int h = 0; h < 64; ++h) {
                    a = fmaf(W_lin[h], W_o[h], a);
                    bb = fmaf(b_lin[h], W_o[h], bb);
                }
                uvs[256] = a;  // wlo
                uvs[257] = bb; // blo
            }
        }
    }
}

// ---------------- tabulate g(y) = sum_k tanh(y*u_k + v_k) * w_k over y in [-32,32] ----------------
__global__ void build_gtab(const float* __restrict__ uvs, const float* __restrict__ W_a2,
                           float* __restrict__ gtab) {
    int i = blockIdx.x * 256 + threadIdx.x;
    if (i > 16384) return;
    float y = fmaf((float)i, 1.f / 256.f, -32.f);
    float s = 0.f;
    for (int k = 0; k < 128; ++k)
        s = fmaf(fast_tanh(fmaf(y, uvs[k], uvs[128 + k])), W_a2[k], s);
    gtab[i] = s;
}

// ---------------- encoder aggregation: agg[dst][0..15] = sum nan_to_num(feat[src])*c_se[src] ----------
__global__ __launch_bounds__(256) void enc_gather(const float* __restrict__ feat,
                                                  const float* __restrict__ deg_se,
                                                  const int* __restrict__ cntE,
                                                  const u32* __restrict__ csrE,
                                                  float* __restrict__ agg) {
    const int tid = threadIdx.x, lane = tid & 63, wid = tid >> 6;
    const int grp = lane >> 2, l = lane & 3;      // 16 quads of 4 lanes
    const int dst = blockIdx.x * 64 + wid * 16 + grp;
    int cnt = cntE[dst];
    if (cnt > SLOTE) cnt = SLOTE;
    const u32* cp = csrE + (size_t)dst * SLOTE;
    float4 a = {0.f, 0.f, 0.f, 0.f};
    if (l < 3) {
        for (int e = 0; e < cnt; e += 4) {
            u32 s0 = cp[e], s1 = cp[e + 1], s2 = cp[e + 2], s3 = cp[e + 3];
            float c0 = rsqrtf(fmaxf(deg_se[s0], 1.0f));
            float c1 = (e + 1 < cnt) ? rsqrtf(fmaxf(deg_se[s1], 1.0f)) : 0.f;
            float c2 = (e + 2 < cnt) ? rsqrtf(fmaxf(deg_se[s2], 1.0f)) : 0.f;
            float c3 = (e + 3 < cnt) ? rsqrtf(fmaxf(deg_se[s3], 1.0f)) : 0.f;
            float4 w0 = *(const float4*)(feat + (size_t)s0 * 12 + l * 4);
            float4 w1 = *(const float4*)(feat + (size_t)s1 * 12 + l * 4);
            float4 w2 = *(const float4*)(feat + (size_t)s2 * 12 + l * 4);
            float4 w3 = *(const float4*)(feat + (size_t)s3 * 12 + l * 4);
            w0.x = (w0.x != w0.x) ? 0.f : w0.x; w0.y = (w0.y != w0.y) ? 0.f : w0.y;
            w0.z = (w0.z != w0.z) ? 0.f : w0.z; w0.w = (w0.w != w0.w) ? 0.f : w0.w;
            w1.x = (w1.x != w1.x) ? 0.f : w1.x; w1.y = (w1.y != w1.y) ? 0.f : w1.y;
            w1.z = (w1.z != w1.z) ? 0.f : w1.z; w1.w = (w1.w != w1.w) ? 0.f : w1.w;
            w2.x = (w2.x != w2.x) ? 0.f : w2.x; w2.y = (w2.y != w2.y) ? 0.f : w2.y;
            w2.z = (w2.z != w2.z) ? 0.f : w2.z; w2.w = (w2.w != w2.w) ? 0.f : w2.w;
            w3.x = (w3.x != w3.x) ? 0.f : w3.x; w3.y = (w3.y != w3.y) ? 0.f : w3.y;
            w3.z = (w3.z != w3.z) ? 0.f : w3.z; w3.w = (w3.w != w3.w) ? 0.f : w3.w;
            a.x = fmaf(w0.x, c0, fmaf(w1.x, c1, fmaf(w2.x, c2, fmaf(w3.x, c3, a.x))));
            a.y = fmaf(w0.y, c0, fmaf(w1.y, c1, fmaf(w2.y, c2, fmaf(w3.y, c3, a.y))));
            a.z = fmaf(w0.z, c0, fmaf(w1.z, c1, fmaf(w2.z, c2, fmaf(w3.z, c3, a.z))));
            a.w = fmaf(w0.w, c0, fmaf(w1.w, c1, fmaf(w2.w, c2, fmaf(w3.w, c3, a.w))));
        }
    }
    *(float4*)(agg + (size_t)dst * 16 + l * 4) = a;   // l==3 writes zero pad
}

// ---------------- all 12 t in one pass: m[c][n][h][tt] fp16, c = t/4 ----------------
__global__ void make_all(const float* __restrict__ agg, const int* __restrict__ cntE,
                         const float* __restrict__ deg_sd, const float* __restrict__ W_enc,
                         const float* __restrict__ b_enc, const float* __restrict__ W_proc,
                         const float* __restrict__ b_proc, u16* __restrict__ m, size_t cstride) {
    int gid = blockIdx.x * 256 + threadIdx.x;
    if (gid >= NH * 64) return;
    int n = gid >> 6, h = gid & 63;
    float cde = rsqrtf(fmaxf((float)cntE[n], 1.0f));
    float csd = rsqrtf(fmaxf(deg_sd[n], 1.0f));
    float he[12];
    #pragma unroll
    for (int ti = 0; ti < 12; ++ti) {
        float a = agg[n * 16 + ti] * cde;
        float x = fmaf(a, W_enc[ti * 64 + h], b_enc[ti * 64 + h]);
        he[ti] = x > 0.f ? x : 0.01f * x;
    }
    #pragma unroll
    for (int c = 0; c < 3; ++c) {
        u16 r[4];
        #pragma unroll
        for (int tt = 0; tt < 4; ++tt) {
            int t = c * 4 + tt;
            float s = b_proc[t];
            #pragma unroll
            for (int ti = 0; ti < 12; ++ti) s = fmaf(he[ti], W_proc[ti * 12 + t], s);
            s = fmaxf(s, 0.f) * csd;
            r[tt] = __half_as_ushort(__float2half(s));
        }
        u32 o0 = ((u32)r[1] << 16) | r[0];
        u32 o1 = ((u32)r[3] << 16) | r[2];
        u32* dst = (u32*)(m + c * cstride + (size_t)n * 256 + h * 4);
        dst[0] = o0; dst[1] = o1;
    }
}

// ---------------- fallback: single chunk m[n][h][tt] for t = t0..t0+3 ----------------
__global__ void make_chunk(const float* __restrict__ agg, const int* __restrict__ cntE,
                           const float* __restrict__ deg_sd, const float* __restrict__ W_enc,
                           const float* __restrict__ b_enc, const float* __restrict__ W_proc,
                           const float* __restrict__ b_proc, u16* __restrict__ m, int t0) {
    int gid = blockIdx.x * 256 + threadIdx.x;
    if (gid >= NH * 64) return;
    int n = gid >> 6, h = gid & 63;
    float cde = rsqrtf(fmaxf((float)cntE[n], 1.0f));
    float csd = rsqrtf(fmaxf(deg_sd[n], 1.0f));
    float he[12];
    #pragma unroll
    for (int ti = 0; ti < 12; ++ti) {
        float a = agg[n * 16 + ti] * cde;
        float x = fmaf(a, W_enc[ti * 64 + h], b_enc[ti * 64 + h]);
        he[ti] = x > 0.f ? x : 0.01f * x;
    }
    u16 r[4];
    #pragma unroll
    for (int tt = 0; tt < 4; ++tt) {
        int t = t0 + tt;
        float s = b_proc[t];
        #pragma unroll
        for (int ti = 0; ti < 12; ++ti) s = fmaf(he[ti], W_proc[ti * 12 + t], s);
        s = fmaxf(s, 0.f) * csd;
        r[tt] = __half_as_ushort(__float2half(s));
    }
    u32 o0 = ((u32)r[1] << 16) | r[0];
    u32 o1 = ((u32)r[3] << 16) | r[2];
    u32* dst = (u32*)(m + (size_t)n * 256 + h * 4);
    dst[0] = o0; dst[1] = o1;
}

// ---------------- decoder pass: chunk = blockIdx.y; gather + MFMA GEMMs ----------------
__global__ __launch_bounds__(256) void dec_batch(
    const u16* __restrict__ mbase, const int* __restrict__ cntD, const u16* __restrict__ csrD,
    const u16* __restrict__ fragWdec, const u16* __restrict__ fragWa1,
    const float* __restrict__ b_dec, const float* __restrict__ b_a1,
    const float* __restrict__ W_a2, const float* __restrict__ W_o,
    float* __restrict__ S1, float* __restrict__ PW, int t0p, size_t mstride) {
    __shared__ __align__(16) u16 zs[22528];   // 4 waves x (4 tt x 16 rows x 88)

    const u16* m = mbase + (size_t)blockIdx.y * mstride;
    const int t0 = t0p + blockIdx.y * 4;
    const int tid = threadIdx.x, lane = tid & 63, wid = tid >> 6;
    const int nw = blockIdx.x * 64 + wid * 16;
    const int g16 = lane >> 4, c16 = lane & 15;
    u16* zw0 = zs + wid * 5632;

    // ---- hoisted per-node metadata + full csr rows (all independent loads) ----
    int cdw[4]; float cdd[4];
    uint4 q[4][3];
    #pragma unroll
    for (int k = 0; k < 4; ++k) {
        int n = nw + g16 * 4 + k;
        bool v = (n < NF);
        int nn = v ? n : 0;
        int cd = cntD[nn];
        cdd[k] = v ? rsqrtf(fmaxf((float)cd, 1.0f)) : 0.f;
        cdw[k] = v ? (cd > SLOTD ? SLOTD : cd) : 0;
        const uint4* cp4 = (const uint4*)(csrD + (size_t)nn * SLOTD);
        q[k][0] = cp4[0]; q[k][1] = cp4[1]; q[k][2] = cp4[2];
    }
    int cdmax = max(max(cdw[0], cdw[1]), max(cdw[2], cdw[3]));

    // acc[k][ch*2 + p]: node k, channel c16*4+ch, tt-pair p
    __half2 acc[4][8];
    #pragma unroll
    for (int k = 0; k < 4; ++k)
        #pragma unroll
        for (int i = 0; i < 8; ++i)
            acc[k][i] = __half2{__half(0.f), __half(0.f)};

    const u16* mrow = m + c16 * 16;
    #pragma unroll
    for (int it = 0; it < 6; ++it) {
        if (it >= 2 && !__any(it * 4 < cdmax)) break;   // wave-uniform early exit
        #pragma unroll
        for (int k = 0; k < 4; ++k) {
            if (it * 4 < cdw[k]) {
                u32 lo = (it & 1) ? q[k][it >> 1].z : q[k][it >> 1].x;
                u32 hi = (it & 1) ? q[k][it >> 1].w : q[k][it >> 1].y;
                int s0 = (int)(lo & 0xFFFF), s1 = (int)(lo >> 16);
                int s2 = (int)(hi & 0xFFFF), s3 = (int)(hi >> 16);
                const uint4* r0 = (const uint4*)(mrow + (size_t)s0 * 256);
                const uint4* r1 = (const uint4*)(mrow + (size_t)s1 * 256);
                const uint4* r2 = (const uint4*)(mrow + (size_t)s2 * 256);
                const uint4* r3 = (const uint4*)(mrow + (size_t)s3 * 256);
                uint4 A0 = r0[0], B0 = r0[1];
                uint4 A1 = r1[0], B1 = r1[1];
                uint4 A2 = r2[0], B2 = r2[1];
                uint4 A3 = r3[0], B3 = r3[1];
                acc[k][0] = __hadd2(acc[k][0], __hadd2(__hadd2(h2(A0.x), h2(A1.x)), __hadd2(h2(A2.x), h2(A3.x))));
                acc[k][1] = __hadd2(acc[k][1], __hadd2(__hadd2(h2(A0.y), h2(A1.y)), __hadd2(h2(A2.y), h2(A3.y))));
                acc[k][2] = __hadd2(acc[k][2], __hadd2(__hadd2(h2(A0.z), h2(A1.z)), __hadd2(h2(A2.z), h2(A3.z))));
                acc[k][3] = __hadd2(acc[k][3], __hadd2(__hadd2(h2(A0.w), h2(A1.w)), __hadd2(h2(A2.w), h2(A3.w))));
                acc[k][4] = __hadd2(acc[k][4], __hadd2(__hadd2(h2(B0.x), h2(B1.x)), __hadd2(h2(B2.x), h2(B3.x))));
                acc[k][5] = __hadd2(acc[k][5], __hadd2(__hadd2(h2(B0.y), h2(B1.y)), __hadd2(h2(B2.y), h2(B3.y))));
                acc[k][6] = __hadd2(acc[k][6], __hadd2(__hadd2(h2(B0.z), h2(B1.z)), __hadd2(h2(B2.z), h2(B3.z))));
                acc[k][7] = __hadd2(acc[k][7], __hadd2(__hadd2(h2(B0.w), h2(B1.w)), __hadd2(h2(B2.w), h2(B3.w))));
            }
        }
    }

    // ---- stage all 4 tt into LDS (A-operand layout per tt) ----
    #pragma unroll
    for (int k = 0; k < 4; ++k) {
        int j = g16 * 4 + k;
        float s = cdd[k];
        #pragma unroll
        for (int p = 0; p < 2; ++p) {
            float2 c0 = __half22float2(acc[k][0 * 2 + p]);
            float2 c1 = __half22float2(acc[k][1 * 2 + p]);
            float2 c2 = __half22float2(acc[k][2 * 2 + p]);
            float2 c3 = __half22float2(acc[k][3 * 2 + p]);
            u32 oA0 = ((u32)f2b(c1.x * s) << 16) | f2b(c0.x * s);
            u32 oA1 = ((u32)f2b(c3.x * s) << 16) | f2b(c2.x * s);
            u32 oB0 = ((u32)f2b(c1.y * s) << 16) | f2b(c0.y * s);
            u32 oB1 = ((u32)f2b(c3.y * s) << 16) | f2b(c2.y * s);
            u32* dA = (u32*)(zw0 + (2 * p) * 1408 + j * 88 + c16 * 4);
            u32* dB = (u32*)(zw0 + (2 * p + 1) * 1408 + j * 88 + c16 * 4);
            dA[0] = oA0; dA[1] = oA1;
            dB[0] = oB0; dB[1] = oB1;
        }
    }
    asm volatile("s_waitcnt lgkmcnt(0)" ::: "memory");   // wave-local zs ready

    // ---- per-t GEMM pipeline (B-fragments streamed from L2; no __syncthreads) ----
    for (int tt = 0; tt < 4; ++tt) {
        const int t = t0 + tt;
        u16* zw = zw0 + tt * 1408;
        const u16* ab = zw + c16 * 88 + g16 * 8;
        short8 a0 = *(const short8*)ab;            // A[m=c16][k=g16*8+j]
        short8 a1 = *(const short8*)(ab + 32);     // k += 32

        const u16* fw = fragWdec + (size_t)t * 4096;
        float4v C1[4];
        #pragma unroll
        for (int cc = 0; cc < 4; ++cc) {
            float4v z4 = {0.f, 0.f, 0.f, 0.f};
            short8 b0 = *(const short8*)(fw + (cc * 2 + 0) * 512 + lane * 8);
            short8 b1 = *(const short8*)(fw + (cc * 2 + 1) * 512 + lane * 8);
            z4 = __builtin_amdgcn_mfma_f32_16x16x32_bf16(a0, b0, z4, 0, 0, 0);
            C1[cc] = __builtin_amdgcn_mfma_f32_16x16x32_bf16(a1, b1, z4, 0, 0, 0);
        }

        float pw[4] = {0.f, 0.f, 0.f, 0.f};
        #pragma unroll
        for (int cc = 0; cc < 4; ++cc) {
            float bt = b_dec[t * 64 + cc * 16 + c16];
            float wo = W_o[cc * 16 + c16];
            #pragma unroll
            for (int r = 0; r < 4; ++r) {
                float xx = C1[cc][r] + bt;            // C row(node)=g16*4+r, col=cc*16+c16
                float sp = xx > 0.f ? xx : 0.01f * xx;
                pw[r] = fmaf(sp, wo, pw[r]);
                zw[(g16 * 4 + r) * 88 + cc * 16 + c16] = f2b(sp);
            }
        }
        asm volatile("s_waitcnt lgkmcnt(0)" ::: "memory");
        short8 sa0 = *(const short8*)ab;
        short8 sa1 = *(const short8*)(ab + 32);

        float4v C2[8];
        #pragma unroll
        for (int cc = 0; cc < 8; ++cc) {
            float4v z4 = {0.f, 0.f, 0.f, 0.f};
            short8 b0 = *(const short8*)(fragWa1 + (cc * 2 + 0) * 512 + lane * 8);
            short8 b1 = *(const short8*)(fragWa1 + (cc * 2 + 1) * 512 + lane * 8);
            z4 = __builtin_amdgcn_mfma_f32_16x16x32_bf16(sa0, b0, z4, 0, 0, 0);
            C2[cc] = __builtin_amdgcn_mfma_f32_16x16x32_bf16(sa1, b1, z4, 0, 0, 0);
        }

        float p1[4] = {0.f, 0.f, 0.f, 0.f};
        #pragma unroll
        for (int cc = 0; cc < 8; ++cc) {
            int k = cc * 16 + c16;
            float ba = b_a1[k], wa = W_a2[k];
            #pragma unroll
            for (int r = 0; r < 4; ++r)
                p1[r] = fmaf(fast_tanh(C2[cc][r] + ba), wa, p1[r]);
        }

        #pragma unroll
        for (int mm = 1; mm < 16; mm <<= 1) {
            #pragma unroll
            for (int r = 0; r < 4; ++r) {
                p1[r] += __shfl_xor(p1[r], mm);
                pw[r] += __shfl_xor(pw[r], mm);
            }
        }

        if (c16 == 0) {
            #pragma unroll
            for (int r = 0; r < 4; ++r) {
                int n = nw + g16 * 4 + r;
                if (n < NF) {
                    S1[(size_t)t * NF + n] = p1[r];
                    PW[(size_t)t * NF + n] = pw[r];
                }
            }
        }
    }
}

// ---------------- 12-step scalar recurrence: 1 thread per node, table-lerp for s2 ----------------
__global__ __launch_bounds__(256) void dec_scan(
    const float* __restrict__ S1, const float* __restrict__ PW,
    const float* __restrict__ gtab, const float* __restrict__ uvs,
    const float* __restrict__ feat, const float* __restrict__ b_a2p,
    const float* __restrict__ b_op, float* __restrict__ out) {
    const int n = blockIdx.x * 256 + threadIdx.x;
    if (n >= NF) return;
    float s1v[12], pwv[12];
    #pragma unroll
    for (int t = 0; t < 12; ++t) {
        s1v[t] = S1[(size_t)t * NF + n];
        pwv[t] = PW[(size_t)t * NF + n];
    }
    const float wlo = uvs[256], blo = uvs[257], ba2 = b_a2p[0], bo = b_op[0];
    float yp = feat[n * 12 + 11];
    yp = (yp != yp) ? 0.f : yp;
    #pragma unroll
    for (int t = 0; t < 12; ++t) {
        float xf = fminf(fmaxf(fmaf(yp, 256.f, 8192.f), 0.f), 16383.f);
        int idx = (int)xf;
        float fr = xf - (float)idx;
        float g0 = gtab[idx], g1 = gtab[idx + 1];
        float p2 = fmaf(g1 - g0, fr, g0);
        float s1s = s1v[t] + ba2, s2s = p2 + ba2;
        float mx = fmaxf(s1s, s2s);
        float e1 = __expf(s1s - mx), e2 = __expf(s2s - mx);
        float y = (e1 * pwv[t] + e2 * fmaf(wlo, yp, blo)) / (e1 + e2) + bo;
        out[(size_t)t * NF + n] = y;
        yp = y;
    }
}

// ---------------- launch ----------------
extern "C" void kernel_launch(void* const* d_in, const int* in_sizes, int n_in,
                              void* d_out, int out_size, void* d_ws, size_t ws_size,
                              hipStream_t stream) {
    const float* feat   = (const float*)d_in[0];
    const int* enc_src  = (const int*)d_in[1];
    const int* enc_dst  = (const int*)d_in[2];
    const int* dec_src  = (const int*)d_in[3];
    const int* dec_dst  = (const int*)d_in[4];
    const float* W_enc  = (const float*)d_in[5];
    const float* b_enc  = (const float*)d_in[6];
    const float* W_proc = (const float*)d_in[7];
    const float* b_proc = (const float*)d_in[8];
    const float* W_dec  = (const float*)d_in[9];
    const float* b_dec  = (const float*)d_in[10];
    const float* W_lin  = (const float*)d_in[11];
    const float* b_lin  = (const float*)d_in[12];
    const float* W_a1   = (const float*)d_in[13];
    const float* b_a1   = (const float*)d_in[14];
    const float* W_a2   = (const float*)d_in[15];
    const float* b_a2   = (const float*)d_in[16];
    const float* W_o    = (const float*)d_in[17];
    const float* b_o    = (const float*)d_in[18];
    float* out = (float*)d_out;

    float* W = (float*)d_ws;
    float* deg_se   = W;                       // NF                 0 .. 100000
    float* deg_sd   = W + 100000;              // NH                 .. 149152
    int*   cntD     = (int*)(W + 149152);      // NF                 .. 249152
    int*   cntE     = (int*)(W + 249152);      // NH                 .. 298304
    float* uvs      = W + 298304;              // 260 -> pad 298624
    u16*   fragWdec = (u16*)(W + 298624);      // 49152 u16          .. 323200
    u16*   fragWa1  = (u16*)(W + 323200);      // 8192 u16           .. 327296
    float* agg      = W + 327296;              // NH*16              .. 1113728
    float* S1       = W + 1113728;             // 12*NF              .. 2313728
    float* PW       = W + 2313728;             // 12*NF              .. 3513728
    u16*   csrD     = (u16*)(W + 3513728);     // NF*24 u16          .. 4713728
    u32*   csrE     = (u32*)(W + 4713728);     // NH*32              .. 6286592
    float* gtab     = W + 6286592;             // 16385 -> pad       .. 6303104
    u16*   m_ws     = (u16*)(W + 6303104);     // full: 3*(NH+1)*256 u16; fallback: (NH+1)*256 u16

    const size_t CSTRIDE = (size_t)(NH + 1) * 256;                       // u16 per chunk
    const size_t need_full = ((size_t)6303104 + 3 * CSTRIDE / 2) * 4;    // ~100.7 MB
    const bool full = ws_size >= need_full;
    const int zstride = full ? (int)(CSTRIDE / 2) : 0;                   // u32 units

    const int PTOT = PN1 + PN2 + PN3 + PN4;
    prefill<<<(PTOT + 255) / 256, 256, 0, stream>>>((u32*)csrD, csrE, (u32*)W,
                                                    (u32*)m_ws + (size_t)NH * 128, zstride);
    fill_slotted<<<(EDG + 255) / 256, 256, 0, stream>>>(enc_src, enc_dst, dec_src, dec_dst,
                                                        cntD, csrD, deg_sd, cntE, csrE, deg_se);
    prep_small<<<29, 256, 0, stream>>>(W_dec, W_a1, fragWdec, fragWa1,
                                       W_lin, b_lin, b_a1, W_o, uvs);
    build_gtab<<<65, 256, 0, stream>>>(uvs, W_a2, gtab);
    enc_gather<<<NH / 64, 256, 0, stream>>>(feat, deg_se, cntE, csrE, agg);

    const int dec_grid = (NF + 63) / 64;
    if (full) {
        make_all<<<(NH * 64) / 256, 256, 0, stream>>>(agg, cntE, deg_sd, W_enc, b_enc,
                                                      W_proc, b_proc, m_ws, CSTRIDE);
        dec_batch<<<dim3(dec_grid, 3), 256, 0, stream>>>(m_ws, cntD, csrD, fragWdec, fragWa1,
                                                         b_dec, b_a1, W_a2, W_o, S1, PW,
                                                         0, CSTRIDE);
    } else {
        for (int c = 0; c < 3; ++c) {
            make_chunk<<<(NH * 64) / 256, 256, 0, stream>>>(agg, cntE, deg_sd, W_enc, b_enc,
                                                            W_proc, b_proc, m_ws, 4 * c);
            dec_batch<<<dim3(dec_grid, 1), 256, 0, stream>>>(m_ws, cntD, csrD, fragWdec, fragWa1,
                                                             b_dec, b_a1, W_a2, W_o, S1, PW,
                                                             4 * c, 0);
        }
    }
    dec_scan<<<(NF + 255) / 256, 256, 0, stream>>>(S1, PW, gtab, uvs, feat, b_a2, b_o, out);
}